// Round 1
// baseline (1273.060 us; speedup 1.0000x reference)
//
#include <hip/hip_runtime.h>

// Problem constants (shapes fixed by reference; N/E taken from in_sizes).
// Pipeline:
//   h0 = relu(relu([x|static]@W1+b1)@W2+b2)            [N,64]
//   h1 = relu(gcn(h0, Wg0, bg0))                        [N,128]
//   h2 = relu(gcn(h1, Wg1, bg1))                        [N,128]
//   out = gcn(h2, Wg2, bg2)                             [N,64]
// gcn(x,W,b): hW = x@W; deg=1+indeg(dst); dis=rsqrt(deg);
//   out[i] = sum_{e: dst=i} hW[src]*dis[src]*dis[i] + hW[i]*dis[i]^2 + b

// ---------------- graph preprocessing (CSR by dst, int atomics only) --------

__global__ void k_count(const int* __restrict__ dst, int* __restrict__ cnt, int e) {
    int i = blockIdx.x * 256 + threadIdx.x;
    if (i < e) atomicAdd(&cnt[dst[i]], 1);
}

__global__ void k_dis(const int* __restrict__ cnt, float* __restrict__ dis, int n) {
    int i = blockIdx.x * 256 + threadIdx.x;
    if (i < n) dis[i] = rsqrtf(1.0f + (float)cnt[i]);
}

__global__ void k_blocksum(const int* __restrict__ cnt, int* __restrict__ bsum, int n) {
    __shared__ int sm[256];
    int t = threadIdx.x;
    int base = blockIdx.x * 1024;
    int s = 0;
#pragma unroll
    for (int i = 0; i < 4; i++) {
        int idx = base + i * 256 + t;
        if (idx < n) s += cnt[idx];
    }
    sm[t] = s;
    __syncthreads();
    for (int off = 128; off > 0; off >>= 1) {
        if (t < off) sm[t] += sm[t + off];
        __syncthreads();
    }
    if (t == 0) bsum[blockIdx.x] = sm[0];
}

// single block, exclusive scan of block sums (nb <= 256)
__global__ void k_scansums(const int* __restrict__ bsum, int* __restrict__ boff, int nb) {
    __shared__ int sm[256];
    int t = threadIdx.x;
    int v = (t < nb) ? bsum[t] : 0;
    sm[t] = v;
    __syncthreads();
    for (int off = 1; off < 256; off <<= 1) {
        int add = (t >= off) ? sm[t - off] : 0;
        __syncthreads();
        sm[t] += add;
        __syncthreads();
    }
    if (t < nb) boff[t] = sm[t] - v;  // exclusive
}

__global__ void k_scatterscan(const int* __restrict__ cnt, const int* __restrict__ boff,
                              int* __restrict__ offs, int n) {
    __shared__ int sm[256];
    int t = threadIdx.x;
    int base = blockIdx.x * 1024 + t * 4;
    int v[4];
    int s = 0;
#pragma unroll
    for (int i = 0; i < 4; i++) {
        int idx = base + i;
        v[i] = (idx < n) ? cnt[idx] : 0;
        s += v[i];
    }
    sm[t] = s;
    __syncthreads();
    for (int off = 1; off < 256; off <<= 1) {
        int add = (t >= off) ? sm[t - off] : 0;
        __syncthreads();
        sm[t] += add;
        __syncthreads();
    }
    int run = boff[blockIdx.x] + sm[t] - s;  // block base + exclusive prefix of this thread
#pragma unroll
    for (int i = 0; i < 4; i++) {
        int idx = base + i;
        if (idx < n) {
            offs[idx] = run;
            run += v[i];
            if (idx == n - 1) offs[n] = run;
        }
    }
}

__global__ void k_fill(const int* __restrict__ src, const int* __restrict__ dst,
                       const int* __restrict__ offs, int* __restrict__ cur,
                       int* __restrict__ ssrc, int e) {
    int i = blockIdx.x * 256 + threadIdx.x;
    if (i < e) {
        int d = dst[i];
        int p = offs[d] + atomicAdd(&cur[d], 1);
        ssrc[p] = src[i];
    }
}

// ---------------- dense matmul: out[n,FOUT] = in[n,FIN1|FIN2 concat] @ W ----
// Thread = one node; each thread computes 32 consecutive output features
// (f0 = blockIdx.y*32, wave-uniform) so W/bias loads are scalar (s_load) and
// the inner loop is pure v_fmac_f32 with an SGPR operand.

template <int FIN1, int FIN2, int FOUT, bool BIAS, bool RELU>
__global__ void k_mm(const float* __restrict__ in1, const float* __restrict__ in2,
                     const float* __restrict__ W, const float* __restrict__ bias,
                     float* __restrict__ out, int n) {
    int node = blockIdx.x * 256 + threadIdx.x;
    int f0 = blockIdx.y * 32;
    if (node >= n) return;

    float acc[32];
#pragma unroll
    for (int j = 0; j < 32; j++) acc[j] = BIAS ? bias[f0 + j] : 0.0f;

    {
        const float* row = in1 + (size_t)node * FIN1;
        for (int k = 0; k < FIN1; k += 4) {
            float4 a = *(const float4*)(row + k);
#pragma unroll
            for (int kk = 0; kk < 4; kk++) {
                float av = (kk == 0) ? a.x : (kk == 1) ? a.y : (kk == 2) ? a.z : a.w;
                const float* wr = W + (size_t)(k + kk) * FOUT + f0;
#pragma unroll
                for (int j = 0; j < 32; j++) acc[j] = fmaf(av, wr[j], acc[j]);
            }
        }
    }
    if constexpr (FIN2 > 0) {
        const float* row = in2 + (size_t)node * FIN2;
        for (int k = 0; k < FIN2; k += 4) {
            float4 a = *(const float4*)(row + k);
#pragma unroll
            for (int kk = 0; kk < 4; kk++) {
                float av = (kk == 0) ? a.x : (kk == 1) ? a.y : (kk == 2) ? a.z : a.w;
                const float* wr = W + (size_t)(FIN1 + k + kk) * FOUT + f0;
#pragma unroll
                for (int j = 0; j < 32; j++) acc[j] = fmaf(av, wr[j], acc[j]);
            }
        }
    }

    float* orow = out + (size_t)node * FOUT + f0;
#pragma unroll
    for (int j = 0; j < 32; j++) {
        if (RELU) acc[j] = fmaxf(acc[j], 0.0f);
    }
#pragma unroll
    for (int j = 0; j < 32; j += 4) {
        *(float4*)(orow + j) = make_float4(acc[j], acc[j + 1], acc[j + 2], acc[j + 3]);
    }
}

// ---------------- GCN aggregation: one wave per node ------------------------
// out[i] = sum_{j in CSR row} hW[ssrc[j]] * dis[ssrc[j]] * dis[i]
//        + hW[i]*dis[i]^2 + bias   (optional relu)

template <int F, bool RELU>
__global__ void k_agg(const float* __restrict__ hW, const float* __restrict__ bias,
                      const float* __restrict__ dis, const int* __restrict__ offs,
                      const int* __restrict__ ssrc, float* __restrict__ out, int n) {
    int wv = __builtin_amdgcn_readfirstlane(threadIdx.x >> 6);  // force wave-uniform
    int lane = threadIdx.x & 63;
    int node = blockIdx.x * 4 + wv;
    if (node >= n) return;

    constexpr int FPL = F / 64;  // floats per lane (1 or 2)
    float acc[FPL];
#pragma unroll
    for (int q = 0; q < FPL; q++) acc[q] = 0.0f;

    int jb = offs[node];
    int je = offs[node + 1];
    float di = dis[node];
    const float* lbase = hW + lane * FPL;

    for (int j = jb; j < je; j++) {
        int s = ssrc[j];
        float w = dis[s] * di;
        const float* hr = lbase + (size_t)s * F;
#pragma unroll
        for (int q = 0; q < FPL; q++) acc[q] = fmaf(hr[q], w, acc[q]);
    }

    const float* hs = hW + (size_t)node * F + lane * FPL;
    float sw = di * di;
#pragma unroll
    for (int q = 0; q < FPL; q++) {
        float v = acc[q] + hs[q] * sw + bias[lane * FPL + q];
        if (RELU) v = fmaxf(v, 0.0f);
        out[(size_t)node * F + lane * FPL + q] = v;
    }
}

// ---------------- launch -----------------------------------------------------

extern "C" void kernel_launch(void* const* d_in, const int* in_sizes, int n_in,
                              void* d_out, int out_size, void* d_ws, size_t ws_size,
                              hipStream_t stream) {
    const float* x   = (const float*)d_in[0];
    const float* st  = (const float*)d_in[1];
    const int*   src = (const int*)d_in[2];
    const int*   dst = (const int*)d_in[3];
    const float* W1  = (const float*)d_in[4];
    const float* b1  = (const float*)d_in[5];
    const float* W2  = (const float*)d_in[6];
    const float* b2  = (const float*)d_in[7];
    const float* Wg0 = (const float*)d_in[8];
    const float* bg0 = (const float*)d_in[9];
    const float* Wg1 = (const float*)d_in[10];
    const float* bg1 = (const float*)d_in[11];
    const float* Wg2 = (const float*)d_in[12];
    const float* bg2 = (const float*)d_in[13];

    const int n = in_sizes[0] / 64;  // IN_DIM = 64
    const int e = in_sizes[2];

    // workspace carve-out (256B aligned)
    char* wp = (char*)d_ws;
    auto carve = [&](size_t bytes) {
        void* p = (void*)wp;
        wp += (bytes + 255) & ~(size_t)255;
        return p;
    };
    int*   cnt  = (int*)carve((size_t)n * 4);
    int*   cur  = (int*)carve((size_t)n * 4);
    int*   offs = (int*)carve((size_t)(n + 1) * 4);
    float* dis  = (float*)carve((size_t)n * 4);
    int*   ssrc = (int*)carve((size_t)e * 4);
    float* bufA = (float*)carve((size_t)n * 128 * 4);
    float* bufB = (float*)carve((size_t)n * 128 * 4);
    const int nb1024 = (n + 1023) / 1024;
    int* bsum = (int*)carve((size_t)nb1024 * 4);
    int* boff = (int*)carve((size_t)nb1024 * 4);

    hipMemsetAsync(cnt, 0, (size_t)n * 4, stream);
    hipMemsetAsync(cur, 0, (size_t)n * 4, stream);

    const int gE = (e + 255) / 256;
    const int gN = (n + 255) / 256;

    // graph prep
    k_count<<<gE, 256, 0, stream>>>(dst, cnt, e);
    k_dis<<<gN, 256, 0, stream>>>(cnt, dis, n);
    k_blocksum<<<nb1024, 256, 0, stream>>>(cnt, bsum, n);
    k_scansums<<<1, 256, 0, stream>>>(bsum, boff, nb1024);
    k_scatterscan<<<nb1024, 256, 0, stream>>>(cnt, boff, offs, n);
    k_fill<<<gE, 256, 0, stream>>>(src, dst, offs, cur, ssrc, e);

    // MLP: [x|static]@W1+b1 relu -> @W2+b2 relu
    k_mm<64, 32, 128, true, true><<<dim3(gN, 4), 256, 0, stream>>>(x, st, W1, b1, bufA, n);
    k_mm<128, 0, 64, true, true><<<dim3(gN, 2), 256, 0, stream>>>(bufA, nullptr, W2, b2, bufB, n);

    const int gAgg = (n + 3) / 4;

    // conv0: 64 -> 128, relu
    k_mm<64, 0, 128, false, false><<<dim3(gN, 4), 256, 0, stream>>>(bufB, nullptr, Wg0, nullptr, bufA, n);
    k_agg<128, true><<<gAgg, 256, 0, stream>>>(bufA, bg0, dis, offs, ssrc, bufB, n);

    // conv1: 128 -> 128, relu
    k_mm<128, 0, 128, false, false><<<dim3(gN, 4), 256, 0, stream>>>(bufB, nullptr, Wg1, nullptr, bufA, n);
    k_agg<128, true><<<gAgg, 256, 0, stream>>>(bufA, bg1, dis, offs, ssrc, bufB, n);

    // conv2: 128 -> 64, no relu, straight to d_out
    k_mm<128, 0, 64, false, false><<<dim3(gN, 2), 256, 0, stream>>>(bufB, nullptr, Wg2, nullptr, bufA, n);
    k_agg<64, false><<<gAgg, 256, 0, stream>>>(bufA, bg2, dis, offs, ssrc, (float*)d_out, n);
}

// Round 2
// 1262.613 us; speedup vs baseline: 1.0083x; 1.0083x over previous
//
#include <hip/hip_runtime.h>

// Pipeline:
//   h0 = relu(relu([x|static]@W1+b1)@W2+b2)            [N,64]
//   h1 = relu(gcn(h0, Wg0, bg0))                        [N,128]
//   h2 = relu(gcn(h1, Wg1, bg1))                        [N,128]
//   out = gcn(h2, Wg2, bg2)                             [N,64]
// gcn(x,W,b): hW = x@W; deg=1+indeg(dst); dis=rsqrt(deg);
//   out[i] = sum_{e: dst=i} hW[src]*dis[src]*dis[i] + hW[i]*dis[i]^2 + b

// ---------------- graph preprocessing (CSR by dst, int atomics only) --------

__global__ void k_count(const int* __restrict__ dst, int* __restrict__ cnt, int e) {
    int i = blockIdx.x * 256 + threadIdx.x;
    if (i < e) atomicAdd(&cnt[dst[i]], 1);
}

__global__ void k_dis(const int* __restrict__ cnt, float* __restrict__ dis, int n) {
    int i = blockIdx.x * 256 + threadIdx.x;
    if (i < n) dis[i] = rsqrtf(1.0f + (float)cnt[i]);
}

__global__ void k_blocksum(const int* __restrict__ cnt, int* __restrict__ bsum, int n) {
    __shared__ int sm[256];
    int t = threadIdx.x;
    int base = blockIdx.x * 1024;
    int s = 0;
#pragma unroll
    for (int i = 0; i < 4; i++) {
        int idx = base + i * 256 + t;
        if (idx < n) s += cnt[idx];
    }
    sm[t] = s;
    __syncthreads();
    for (int off = 128; off > 0; off >>= 1) {
        if (t < off) sm[t] += sm[t + off];
        __syncthreads();
    }
    if (t == 0) bsum[blockIdx.x] = sm[0];
}

// single block, exclusive scan of block sums (nb <= 256)
__global__ void k_scansums(const int* __restrict__ bsum, int* __restrict__ boff, int nb) {
    __shared__ int sm[256];
    int t = threadIdx.x;
    int v = (t < nb) ? bsum[t] : 0;
    sm[t] = v;
    __syncthreads();
    for (int off = 1; off < 256; off <<= 1) {
        int add = (t >= off) ? sm[t - off] : 0;
        __syncthreads();
        sm[t] += add;
        __syncthreads();
    }
    if (t < nb) boff[t] = sm[t] - v;  // exclusive
}

__global__ void k_scatterscan(const int* __restrict__ cnt, const int* __restrict__ boff,
                              int* __restrict__ offs, int n) {
    __shared__ int sm[256];
    int t = threadIdx.x;
    int base = blockIdx.x * 1024 + t * 4;
    int v[4];
    int s = 0;
#pragma unroll
    for (int i = 0; i < 4; i++) {
        int idx = base + i;
        v[i] = (idx < n) ? cnt[idx] : 0;
        s += v[i];
    }
    sm[t] = s;
    __syncthreads();
    for (int off = 1; off < 256; off <<= 1) {
        int add = (t >= off) ? sm[t - off] : 0;
        __syncthreads();
        sm[t] += add;
        __syncthreads();
    }
    int run = boff[blockIdx.x] + sm[t] - s;  // block base + exclusive prefix of this thread
#pragma unroll
    for (int i = 0; i < 4; i++) {
        int idx = base + i;
        if (idx < n) {
            offs[idx] = run;
            run += v[i];
            if (idx == n - 1) offs[n] = run;
        }
    }
}

__global__ void k_fill(const int* __restrict__ src, const int* __restrict__ dst,
                       const int* __restrict__ offs, int* __restrict__ cur,
                       int* __restrict__ ssrc, int e) {
    int i = blockIdx.x * 256 + threadIdx.x;
    if (i < e) {
        int d = dst[i];
        int p = offs[d] + atomicAdd(&cur[d], 1);
        ssrc[p] = src[i];
    }
}

// ---------------- dense matmul: out[n,FOUT] = in[n,FIN1|FIN2 concat] @ W ----
// Thread = one node; each thread computes 32 consecutive output features
// (f0 = blockIdx.y*32, wave-uniform). W/bias addresses are wave-uniform ->
// scalar (s_load) reads; inner loop is v_fmac_f32 with an SGPR operand.
// Accumulators are EXPLICIT float4 variables (R1 lesson: float acc[32] was
// demoted to scratch -> 780 MB/dispatch of spill traffic, VGPR_Count=20).

__device__ __forceinline__ void fma_blk(float a, const float* __restrict__ wr,
                                        float4& c0, float4& c1, float4& c2, float4& c3,
                                        float4& c4, float4& c5, float4& c6, float4& c7) {
    const float4* w = (const float4*)wr;
    float4 t;
    t = w[0]; c0.x = fmaf(a, t.x, c0.x); c0.y = fmaf(a, t.y, c0.y); c0.z = fmaf(a, t.z, c0.z); c0.w = fmaf(a, t.w, c0.w);
    t = w[1]; c1.x = fmaf(a, t.x, c1.x); c1.y = fmaf(a, t.y, c1.y); c1.z = fmaf(a, t.z, c1.z); c1.w = fmaf(a, t.w, c1.w);
    t = w[2]; c2.x = fmaf(a, t.x, c2.x); c2.y = fmaf(a, t.y, c2.y); c2.z = fmaf(a, t.z, c2.z); c2.w = fmaf(a, t.w, c2.w);
    t = w[3]; c3.x = fmaf(a, t.x, c3.x); c3.y = fmaf(a, t.y, c3.y); c3.z = fmaf(a, t.z, c3.z); c3.w = fmaf(a, t.w, c3.w);
    t = w[4]; c4.x = fmaf(a, t.x, c4.x); c4.y = fmaf(a, t.y, c4.y); c4.z = fmaf(a, t.z, c4.z); c4.w = fmaf(a, t.w, c4.w);
    t = w[5]; c5.x = fmaf(a, t.x, c5.x); c5.y = fmaf(a, t.y, c5.y); c5.z = fmaf(a, t.z, c5.z); c5.w = fmaf(a, t.w, c5.w);
    t = w[6]; c6.x = fmaf(a, t.x, c6.x); c6.y = fmaf(a, t.y, c6.y); c6.z = fmaf(a, t.z, c6.z); c6.w = fmaf(a, t.w, c6.w);
    t = w[7]; c7.x = fmaf(a, t.x, c7.x); c7.y = fmaf(a, t.y, c7.y); c7.z = fmaf(a, t.z, c7.z); c7.w = fmaf(a, t.w, c7.w);
}

__device__ __forceinline__ void relu4(float4& c) {
    c.x = fmaxf(c.x, 0.0f); c.y = fmaxf(c.y, 0.0f);
    c.z = fmaxf(c.z, 0.0f); c.w = fmaxf(c.w, 0.0f);
}

template <int FIN1, int FIN2, int FOUT, bool BIAS, bool RELU>
__global__ __launch_bounds__(256) void k_mm(const float* __restrict__ in1,
                                            const float* __restrict__ in2,
                                            const float* __restrict__ W,
                                            const float* __restrict__ bias,
                                            float* __restrict__ out, int n) {
    int node = blockIdx.x * 256 + threadIdx.x;
    int f0 = blockIdx.y * 32;
    if (node >= n) return;

    float4 c0, c1, c2, c3, c4, c5, c6, c7;
    if (BIAS) {
        const float4* b4 = (const float4*)(bias + f0);
        c0 = b4[0]; c1 = b4[1]; c2 = b4[2]; c3 = b4[3];
        c4 = b4[4]; c5 = b4[5]; c6 = b4[6]; c7 = b4[7];
    } else {
        c0 = c1 = c2 = c3 = c4 = c5 = c6 = c7 = make_float4(0.f, 0.f, 0.f, 0.f);
    }

    {
        const float* row = in1 + (size_t)node * FIN1;
        const float* wb = W + f0;
        for (int k = 0; k < FIN1; k += 4) {
            float4 a = *(const float4*)(row + k);
            fma_blk(a.x, wb + (size_t)(k + 0) * FOUT, c0, c1, c2, c3, c4, c5, c6, c7);
            fma_blk(a.y, wb + (size_t)(k + 1) * FOUT, c0, c1, c2, c3, c4, c5, c6, c7);
            fma_blk(a.z, wb + (size_t)(k + 2) * FOUT, c0, c1, c2, c3, c4, c5, c6, c7);
            fma_blk(a.w, wb + (size_t)(k + 3) * FOUT, c0, c1, c2, c3, c4, c5, c6, c7);
        }
    }
    if constexpr (FIN2 > 0) {
        const float* row = in2 + (size_t)node * FIN2;
        const float* wb = W + (size_t)FIN1 * FOUT + f0;
        for (int k = 0; k < FIN2; k += 4) {
            float4 a = *(const float4*)(row + k);
            fma_blk(a.x, wb + (size_t)(k + 0) * FOUT, c0, c1, c2, c3, c4, c5, c6, c7);
            fma_blk(a.y, wb + (size_t)(k + 1) * FOUT, c0, c1, c2, c3, c4, c5, c6, c7);
            fma_blk(a.z, wb + (size_t)(k + 2) * FOUT, c0, c1, c2, c3, c4, c5, c6, c7);
            fma_blk(a.w, wb + (size_t)(k + 3) * FOUT, c0, c1, c2, c3, c4, c5, c6, c7);
        }
    }

    if (RELU) {
        relu4(c0); relu4(c1); relu4(c2); relu4(c3);
        relu4(c4); relu4(c5); relu4(c6); relu4(c7);
    }

    float4* orow = (float4*)(out + (size_t)node * FOUT + f0);
    orow[0] = c0; orow[1] = c1; orow[2] = c2; orow[3] = c3;
    orow[4] = c4; orow[5] = c5; orow[6] = c6; orow[7] = c7;
}

// ---------------- GCN aggregation: one wave per node ------------------------
// out[i] = sum_{j in CSR row} hW[ssrc[j]] * dis[ssrc[j]] * dis[i]
//        + hW[i]*dis[i]^2 + bias   (optional relu)

template <int F, bool RELU>
__global__ void k_agg(const float* __restrict__ hW, const float* __restrict__ bias,
                      const float* __restrict__ dis, const int* __restrict__ offs,
                      const int* __restrict__ ssrc, float* __restrict__ out, int n) {
    int wv = __builtin_amdgcn_readfirstlane(threadIdx.x >> 6);  // force wave-uniform
    int lane = threadIdx.x & 63;
    int node = blockIdx.x * 4 + wv;
    if (node >= n) return;

    constexpr int FPL = F / 64;  // floats per lane (1 or 2)
    float acc[FPL];
#pragma unroll
    for (int q = 0; q < FPL; q++) acc[q] = 0.0f;

    int jb = offs[node];
    int je = offs[node + 1];
    float di = dis[node];
    const float* lbase = hW + lane * FPL;

    for (int j = jb; j < je; j++) {
        int s = ssrc[j];
        float w = dis[s] * di;
        const float* hr = lbase + (size_t)s * F;
#pragma unroll
        for (int q = 0; q < FPL; q++) acc[q] = fmaf(hr[q], w, acc[q]);
    }

    const float* hs = hW + (size_t)node * F + lane * FPL;
    float sw = di * di;
#pragma unroll
    for (int q = 0; q < FPL; q++) {
        float v = acc[q] + hs[q] * sw + bias[lane * FPL + q];
        if (RELU) v = fmaxf(v, 0.0f);
        out[(size_t)node * F + lane * FPL + q] = v;
    }
}

// ---------------- launch -----------------------------------------------------

extern "C" void kernel_launch(void* const* d_in, const int* in_sizes, int n_in,
                              void* d_out, int out_size, void* d_ws, size_t ws_size,
                              hipStream_t stream) {
    const float* x   = (const float*)d_in[0];
    const float* st  = (const float*)d_in[1];
    const int*   src = (const int*)d_in[2];
    const int*   dst = (const int*)d_in[3];
    const float* W1  = (const float*)d_in[4];
    const float* b1  = (const float*)d_in[5];
    const float* W2  = (const float*)d_in[6];
    const float* b2  = (const float*)d_in[7];
    const float* Wg0 = (const float*)d_in[8];
    const float* bg0 = (const float*)d_in[9];
    const float* Wg1 = (const float*)d_in[10];
    const float* bg1 = (const float*)d_in[11];
    const float* Wg2 = (const float*)d_in[12];
    const float* bg2 = (const float*)d_in[13];

    const int n = in_sizes[0] / 64;  // IN_DIM = 64
    const int e = in_sizes[2];

    // workspace carve-out (256B aligned)
    char* wp = (char*)d_ws;
    auto carve = [&](size_t bytes) {
        void* p = (void*)wp;
        wp += (bytes + 255) & ~(size_t)255;
        return p;
    };
    int*   cnt  = (int*)carve((size_t)n * 4);
    int*   cur  = (int*)carve((size_t)n * 4);
    int*   offs = (int*)carve((size_t)(n + 1) * 4);
    float* dis  = (float*)carve((size_t)n * 4);
    int*   ssrc = (int*)carve((size_t)e * 4);
    float* bufA = (float*)carve((size_t)n * 128 * 4);
    float* bufB = (float*)carve((size_t)n * 128 * 4);
    const int nb1024 = (n + 1023) / 1024;
    int* bsum = (int*)carve((size_t)nb1024 * 4);
    int* boff = (int*)carve((size_t)nb1024 * 4);

    hipMemsetAsync(cnt, 0, (size_t)n * 4, stream);
    hipMemsetAsync(cur, 0, (size_t)n * 4, stream);

    const int gE = (e + 255) / 256;
    const int gN = (n + 255) / 256;

    // graph prep
    k_count<<<gE, 256, 0, stream>>>(dst, cnt, e);
    k_dis<<<gN, 256, 0, stream>>>(cnt, dis, n);
    k_blocksum<<<nb1024, 256, 0, stream>>>(cnt, bsum, n);
    k_scansums<<<1, 256, 0, stream>>>(bsum, boff, nb1024);
    k_scatterscan<<<nb1024, 256, 0, stream>>>(cnt, boff, offs, n);
    k_fill<<<gE, 256, 0, stream>>>(src, dst, offs, cur, ssrc, e);

    // MLP: [x|static]@W1+b1 relu -> @W2+b2 relu
    k_mm<64, 32, 128, true, true><<<dim3(gN, 4), 256, 0, stream>>>(x, st, W1, b1, bufA, n);
    k_mm<128, 0, 64, true, true><<<dim3(gN, 2), 256, 0, stream>>>(bufA, nullptr, W2, b2, bufB, n);

    const int gAgg = (n + 3) / 4;

    // conv0: 64 -> 128, relu
    k_mm<64, 0, 128, false, false><<<dim3(gN, 4), 256, 0, stream>>>(bufB, nullptr, Wg0, nullptr, bufA, n);
    k_agg<128, true><<<gAgg, 256, 0, stream>>>(bufA, bg0, dis, offs, ssrc, bufB, n);

    // conv1: 128 -> 128, relu
    k_mm<128, 0, 128, false, false><<<dim3(gN, 4), 256, 0, stream>>>(bufB, nullptr, Wg1, nullptr, bufA, n);
    k_agg<128, true><<<gAgg, 256, 0, stream>>>(bufA, bg1, dis, offs, ssrc, bufB, n);

    // conv2: 128 -> 64, no relu, straight to d_out
    k_mm<128, 0, 64, false, false><<<dim3(gN, 2), 256, 0, stream>>>(bufB, nullptr, Wg2, nullptr, bufA, n);
    k_agg<64, false><<<gAgg, 256, 0, stream>>>(bufA, bg2, dis, offs, ssrc, (float*)d_out, n);
}

// Round 3
// 869.793 us; speedup vs baseline: 1.4636x; 1.4516x over previous
//
#include <hip/hip_runtime.h>

// Pipeline:
//   h0 = relu(relu([x|static]@W1+b1)@W2+b2)            [N,64]
//   h1 = relu(gcn(h0, Wg0, bg0))                        [N,128]
//   h2 = relu(gcn(h1, Wg1, bg1))                        [N,128]
//   out = gcn(h2, Wg2, bg2)                             [N,64]
// gcn(x,W,b): hW = x@W; deg=1+indeg(dst); dis=rsqrt(deg);
//   out[i] = sum_{e: dst=i} hW[src]*dis[src]*dis[i] + hW[i]*dis[i]^2 + b
//
// R2 lesson: thread=node with per-thread row loads -> 512B-stride float4
// gathers, 4x cache-line over-fetch + L1 thrash (FETCH 774MB vs 51MB ideal,
// VALUBusy 8%). R3: stage the 64-node A-tile in LDS (coalesced), one block
// computes ALL FOUT outputs (no y-slice re-reads).

// ---------------- graph preprocessing (CSR by dst, int atomics only) --------

__global__ void k_count(const int* __restrict__ dst, int* __restrict__ cnt, int e) {
    int i = blockIdx.x * 256 + threadIdx.x;
    if (i < e) atomicAdd(&cnt[dst[i]], 1);
}

__global__ void k_dis(const int* __restrict__ cnt, float* __restrict__ dis, int n) {
    int i = blockIdx.x * 256 + threadIdx.x;
    if (i < n) dis[i] = rsqrtf(1.0f + (float)cnt[i]);
}

__global__ void k_blocksum(const int* __restrict__ cnt, int* __restrict__ bsum, int n) {
    __shared__ int sm[256];
    int t = threadIdx.x;
    int base = blockIdx.x * 1024;
    int s = 0;
#pragma unroll
    for (int i = 0; i < 4; i++) {
        int idx = base + i * 256 + t;
        if (idx < n) s += cnt[idx];
    }
    sm[t] = s;
    __syncthreads();
    for (int off = 128; off > 0; off >>= 1) {
        if (t < off) sm[t] += sm[t + off];
        __syncthreads();
    }
    if (t == 0) bsum[blockIdx.x] = sm[0];
}

// single block, exclusive scan of block sums (nb <= 256)
__global__ void k_scansums(const int* __restrict__ bsum, int* __restrict__ boff, int nb) {
    __shared__ int sm[256];
    int t = threadIdx.x;
    int v = (t < nb) ? bsum[t] : 0;
    sm[t] = v;
    __syncthreads();
    for (int off = 1; off < 256; off <<= 1) {
        int add = (t >= off) ? sm[t - off] : 0;
        __syncthreads();
        sm[t] += add;
        __syncthreads();
    }
    if (t < nb) boff[t] = sm[t] - v;  // exclusive
}

__global__ void k_scatterscan(const int* __restrict__ cnt, const int* __restrict__ boff,
                              int* __restrict__ offs, int n) {
    __shared__ int sm[256];
    int t = threadIdx.x;
    int base = blockIdx.x * 1024 + t * 4;
    int v[4];
    int s = 0;
#pragma unroll
    for (int i = 0; i < 4; i++) {
        int idx = base + i;
        v[i] = (idx < n) ? cnt[idx] : 0;
        s += v[i];
    }
    sm[t] = s;
    __syncthreads();
    for (int off = 1; off < 256; off <<= 1) {
        int add = (t >= off) ? sm[t - off] : 0;
        __syncthreads();
        sm[t] += add;
        __syncthreads();
    }
    int run = boff[blockIdx.x] + sm[t] - s;
#pragma unroll
    for (int i = 0; i < 4; i++) {
        int idx = base + i;
        if (idx < n) {
            offs[idx] = run;
            run += v[i];
            if (idx == n - 1) offs[n] = run;
        }
    }
}

__global__ void k_fill(const int* __restrict__ src, const int* __restrict__ dst,
                       const int* __restrict__ offs, int* __restrict__ cur,
                       int* __restrict__ ssrc, int e) {
    int i = blockIdx.x * 256 + threadIdx.x;
    if (i < e) {
        int d = dst[i];
        int p = offs[d] + atomicAdd(&cur[d], 1);
        ssrc[p] = src[i];
    }
}

// ---------------- dense matmul: out[n,FOUT] = [in1|in2] @ W -----------------
// Block = 64 nodes x FOUT outputs. 256 threads = 4 f-slices x 64 lanes
// (lane = node). A-tile (64 x FINT) staged in LDS via coalesced float4;
// W/bias addresses wave-uniform (readfirstlane) -> s_load; inner loop is
// ds_read_b128 + v_fmac with SGPR operand into named float4 accumulators.

template <int FIN1, int FIN2, int FOUT, bool BIAS, bool RELU>
__global__ __launch_bounds__(256) void k_mm(const float* __restrict__ in1,
                                            const float* __restrict__ in2,
                                            const float* __restrict__ W,
                                            const float* __restrict__ bias,
                                            float* __restrict__ out, int n) {
    constexpr int FINT = FIN1 + FIN2;
    constexpr int ROWF = FINT + 4;   // +4 floats pad: b128 reads 8-way, hidden
    constexpr int JPT = FOUT / 4;    // outputs per thread (32 or 16)
    constexpr int NC4 = JPT / 4;     // float4 accumulators (8 or 4)

    __shared__ float lds[64 * ROWF];

    const int t = threadIdx.x;
    const int base = blockIdx.x * 64;

    // stage in1 (64 rows x FIN1), fully coalesced
    {
        constexpr int R4 = FIN1 / 4;
        const float4* g = (const float4*)in1;
        for (int i = t; i < 64 * R4; i += 256) {
            int r = i / R4, c = i % R4;
            float4 v = (base + r < n) ? g[(size_t)(base + r) * R4 + c]
                                      : make_float4(0.f, 0.f, 0.f, 0.f);
            *(float4*)&lds[r * ROWF + c * 4] = v;
        }
    }
    if constexpr (FIN2 > 0) {
        constexpr int R4 = FIN2 / 4;
        const float4* g = (const float4*)in2;
        for (int i = t; i < 64 * R4; i += 256) {
            int r = i / R4, c = i % R4;
            float4 v = (base + r < n) ? g[(size_t)(base + r) * R4 + c]
                                      : make_float4(0.f, 0.f, 0.f, 0.f);
            *(float4*)&lds[r * ROWF + FIN1 + c * 4] = v;
        }
    }
    __syncthreads();

    const int lane = t & 63;
    const int f0 = __builtin_amdgcn_readfirstlane((t >> 6) * JPT);

    float4 c0, c1, c2, c3, c4, c5, c6, c7;
    if (BIAS) {
        const float4* b4 = (const float4*)(bias + f0);
        c0 = b4[0]; c1 = b4[1]; c2 = b4[2]; c3 = b4[3];
        if (NC4 == 8) { c4 = b4[4]; c5 = b4[5]; c6 = b4[6]; c7 = b4[7]; }
        else { c4 = c5 = c6 = c7 = make_float4(0.f, 0.f, 0.f, 0.f); }
    } else {
        c0 = c1 = c2 = c3 = c4 = c5 = c6 = c7 = make_float4(0.f, 0.f, 0.f, 0.f);
    }

#define FMA_BLK(av, wp)                                                                              \
    do {                                                                                             \
        const float4* _w4 = (const float4*)(wp);                                                     \
        { float4 _t = _w4[0]; c0.x = fmaf(av, _t.x, c0.x); c0.y = fmaf(av, _t.y, c0.y);              \
          c0.z = fmaf(av, _t.z, c0.z); c0.w = fmaf(av, _t.w, c0.w); }                                \
        { float4 _t = _w4[1]; c1.x = fmaf(av, _t.x, c1.x); c1.y = fmaf(av, _t.y, c1.y);              \
          c1.z = fmaf(av, _t.z, c1.z); c1.w = fmaf(av, _t.w, c1.w); }                                \
        { float4 _t = _w4[2]; c2.x = fmaf(av, _t.x, c2.x); c2.y = fmaf(av, _t.y, c2.y);              \
          c2.z = fmaf(av, _t.z, c2.z); c2.w = fmaf(av, _t.w, c2.w); }                                \
        { float4 _t = _w4[3]; c3.x = fmaf(av, _t.x, c3.x); c3.y = fmaf(av, _t.y, c3.y);              \
          c3.z = fmaf(av, _t.z, c3.z); c3.w = fmaf(av, _t.w, c3.w); }                                \
        if constexpr (NC4 == 8) {                                                                    \
            { float4 _t = _w4[4]; c4.x = fmaf(av, _t.x, c4.x); c4.y = fmaf(av, _t.y, c4.y);          \
              c4.z = fmaf(av, _t.z, c4.z); c4.w = fmaf(av, _t.w, c4.w); }                            \
            { float4 _t = _w4[5]; c5.x = fmaf(av, _t.x, c5.x); c5.y = fmaf(av, _t.y, c5.y);          \
              c5.z = fmaf(av, _t.z, c5.z); c5.w = fmaf(av, _t.w, c5.w); }                            \
            { float4 _t = _w4[6]; c6.x = fmaf(av, _t.x, c6.x); c6.y = fmaf(av, _t.y, c6.y);          \
              c6.z = fmaf(av, _t.z, c6.z); c6.w = fmaf(av, _t.w, c6.w); }                            \
            { float4 _t = _w4[7]; c7.x = fmaf(av, _t.x, c7.x); c7.y = fmaf(av, _t.y, c7.y);          \
              c7.z = fmaf(av, _t.z, c7.z); c7.w = fmaf(av, _t.w, c7.w); }                            \
        }                                                                                            \
    } while (0)

    const float* arow = &lds[lane * ROWF];
    for (int k = 0; k < FINT; k += 4) {
        float4 a = *(const float4*)(arow + k);
        const float* wr = W + (size_t)k * FOUT + f0;
        FMA_BLK(a.x, wr);
        FMA_BLK(a.y, wr + FOUT);
        FMA_BLK(a.z, wr + 2 * FOUT);
        FMA_BLK(a.w, wr + 3 * FOUT);
    }
#undef FMA_BLK

    const int node = base + lane;
    if (node < n) {
        if (RELU) {
            c0.x = fmaxf(c0.x, 0.f); c0.y = fmaxf(c0.y, 0.f); c0.z = fmaxf(c0.z, 0.f); c0.w = fmaxf(c0.w, 0.f);
            c1.x = fmaxf(c1.x, 0.f); c1.y = fmaxf(c1.y, 0.f); c1.z = fmaxf(c1.z, 0.f); c1.w = fmaxf(c1.w, 0.f);
            c2.x = fmaxf(c2.x, 0.f); c2.y = fmaxf(c2.y, 0.f); c2.z = fmaxf(c2.z, 0.f); c2.w = fmaxf(c2.w, 0.f);
            c3.x = fmaxf(c3.x, 0.f); c3.y = fmaxf(c3.y, 0.f); c3.z = fmaxf(c3.z, 0.f); c3.w = fmaxf(c3.w, 0.f);
            if (NC4 == 8) {
                c4.x = fmaxf(c4.x, 0.f); c4.y = fmaxf(c4.y, 0.f); c4.z = fmaxf(c4.z, 0.f); c4.w = fmaxf(c4.w, 0.f);
                c5.x = fmaxf(c5.x, 0.f); c5.y = fmaxf(c5.y, 0.f); c5.z = fmaxf(c5.z, 0.f); c5.w = fmaxf(c5.w, 0.f);
                c6.x = fmaxf(c6.x, 0.f); c6.y = fmaxf(c6.y, 0.f); c6.z = fmaxf(c6.z, 0.f); c6.w = fmaxf(c6.w, 0.f);
                c7.x = fmaxf(c7.x, 0.f); c7.y = fmaxf(c7.y, 0.f); c7.z = fmaxf(c7.z, 0.f); c7.w = fmaxf(c7.w, 0.f);
            }
        }
        float4* orow = (float4*)(out + (size_t)node * FOUT + f0);
        orow[0] = c0; orow[1] = c1; orow[2] = c2; orow[3] = c3;
        if (NC4 == 8) { orow[4] = c4; orow[5] = c5; orow[6] = c6; orow[7] = c7; }
    }
}

// ---------------- GCN aggregation: one wave per node ------------------------
// out[i] = sum_{j in CSR row} hW[ssrc[j]] * dis[ssrc[j]] * dis[i]
//        + hW[i]*dis[i]^2 + bias   (optional relu)

template <int F, bool RELU>
__global__ void k_agg(const float* __restrict__ hW, const float* __restrict__ bias,
                      const float* __restrict__ dis, const int* __restrict__ offs,
                      const int* __restrict__ ssrc, float* __restrict__ out, int n) {
    int wv = __builtin_amdgcn_readfirstlane(threadIdx.x >> 6);
    int lane = threadIdx.x & 63;
    int node = blockIdx.x * 4 + wv;
    if (node >= n) return;

    constexpr int FPL = F / 64;  // floats per lane (1 or 2)

    int jb = offs[node];
    int je = offs[node + 1];
    float di = dis[node];

    if constexpr (FPL == 2) {
        float2 acc = make_float2(0.f, 0.f);
        const float* lbase = hW + lane * 2;
        for (int j = jb; j < je; j++) {
            int s = ssrc[j];
            float w = dis[s] * di;
            float2 h = *(const float2*)(lbase + (size_t)s * F);
            acc.x = fmaf(h.x, w, acc.x);
            acc.y = fmaf(h.y, w, acc.y);
        }
        float2 hs = *(const float2*)(hW + (size_t)node * F + lane * 2);
        float2 bb = *(const float2*)(bias + lane * 2);
        float sw = di * di;
        float vx = acc.x + hs.x * sw + bb.x;
        float vy = acc.y + hs.y * sw + bb.y;
        if (RELU) { vx = fmaxf(vx, 0.f); vy = fmaxf(vy, 0.f); }
        *(float2*)(out + (size_t)node * F + lane * 2) = make_float2(vx, vy);
    } else {
        float acc = 0.f;
        const float* lbase = hW + lane;
        for (int j = jb; j < je; j++) {
            int s = ssrc[j];
            float w = dis[s] * di;
            acc = fmaf(lbase[(size_t)s * F], w, acc);
        }
        float hs = hW[(size_t)node * F + lane];
        float v = acc + hs * (di * di) + bias[lane];
        if (RELU) v = fmaxf(v, 0.f);
        out[(size_t)node * F + lane] = v;
    }
}

// ---------------- launch -----------------------------------------------------

extern "C" void kernel_launch(void* const* d_in, const int* in_sizes, int n_in,
                              void* d_out, int out_size, void* d_ws, size_t ws_size,
                              hipStream_t stream) {
    const float* x   = (const float*)d_in[0];
    const float* st  = (const float*)d_in[1];
    const int*   src = (const int*)d_in[2];
    const int*   dst = (const int*)d_in[3];
    const float* W1  = (const float*)d_in[4];
    const float* b1  = (const float*)d_in[5];
    const float* W2  = (const float*)d_in[6];
    const float* b2  = (const float*)d_in[7];
    const float* Wg0 = (const float*)d_in[8];
    const float* bg0 = (const float*)d_in[9];
    const float* Wg1 = (const float*)d_in[10];
    const float* bg1 = (const float*)d_in[11];
    const float* Wg2 = (const float*)d_in[12];
    const float* bg2 = (const float*)d_in[13];

    const int n = in_sizes[0] / 64;  // IN_DIM = 64
    const int e = in_sizes[2];

    char* wp = (char*)d_ws;
    auto carve = [&](size_t bytes) {
        void* p = (void*)wp;
        wp += (bytes + 255) & ~(size_t)255;
        return p;
    };
    int*   cnt  = (int*)carve((size_t)n * 4);
    int*   cur  = (int*)carve((size_t)n * 4);
    int*   offs = (int*)carve((size_t)(n + 1) * 4);
    float* dis  = (float*)carve((size_t)n * 4);
    int*   ssrc = (int*)carve((size_t)e * 4);
    float* bufA = (float*)carve((size_t)n * 128 * 4);
    float* bufB = (float*)carve((size_t)n * 128 * 4);
    const int nb1024 = (n + 1023) / 1024;
    int* bsum = (int*)carve((size_t)nb1024 * 4);
    int* boff = (int*)carve((size_t)nb1024 * 4);

    hipMemsetAsync(cnt, 0, (size_t)n * 4, stream);
    hipMemsetAsync(cur, 0, (size_t)n * 4, stream);

    const int gE = (e + 255) / 256;
    const int gN = (n + 255) / 256;
    const int gN64 = (n + 63) / 64;

    // graph prep
    k_count<<<gE, 256, 0, stream>>>(dst, cnt, e);
    k_dis<<<gN, 256, 0, stream>>>(cnt, dis, n);
    k_blocksum<<<nb1024, 256, 0, stream>>>(cnt, bsum, n);
    k_scansums<<<1, 256, 0, stream>>>(bsum, boff, nb1024);
    k_scatterscan<<<nb1024, 256, 0, stream>>>(cnt, boff, offs, n);
    k_fill<<<gE, 256, 0, stream>>>(src, dst, offs, cur, ssrc, e);

    // MLP: [x|static]@W1+b1 relu -> @W2+b2 relu
    k_mm<64, 32, 128, true, true><<<gN64, 256, 0, stream>>>(x, st, W1, b1, bufA, n);
    k_mm<128, 0, 64, true, true><<<gN64, 256, 0, stream>>>(bufA, nullptr, W2, b2, bufB, n);

    const int gAgg = (n + 3) / 4;

    // conv0: 64 -> 128, relu
    k_mm<64, 0, 128, false, false><<<gN64, 256, 0, stream>>>(bufB, nullptr, Wg0, nullptr, bufA, n);
    k_agg<128, true><<<gAgg, 256, 0, stream>>>(bufA, bg0, dis, offs, ssrc, bufB, n);

    // conv1: 128 -> 128, relu
    k_mm<128, 0, 128, false, false><<<gN64, 256, 0, stream>>>(bufB, nullptr, Wg1, nullptr, bufA, n);
    k_agg<128, true><<<gAgg, 256, 0, stream>>>(bufA, bg1, dis, offs, ssrc, bufB, n);

    // conv2: 128 -> 64, no relu, straight to d_out
    k_mm<128, 0, 64, false, false><<<gN64, 256, 0, stream>>>(bufB, nullptr, Wg2, nullptr, bufA, n);
    k_agg<64, false><<<gAgg, 256, 0, stream>>>(bufA, bg2, dis, offs, ssrc, (float*)d_out, n);
}

// Round 6
// 846.820 us; speedup vs baseline: 1.5033x; 1.0271x over previous
//
#include <hip/hip_runtime.h>

// Pipeline (R3 reference-faithful order and numerics):
//   A = relu([x|st]@W1+b1)            [N,128]  mm1
//   B = relu(A@W2+b2)                 [N,64]   mm2 (h0)
//   A = B@Wg0                         [N,128]  mm3
//   B = relu(agg(A) + bg0)            [N,128]  agg1 (h1)
//   A = B@Wg1                         [N,128]  mm4
//   B = relu(agg(A) + bg1)            [N,128]  agg2 (h2)
//   A = B@Wg2                         [N,64]   mm5
//   out = agg(A) + bg2                [N,64]   agg3
// agg(hW)[i] = sum_{j in CSR row i} hW[ssrc[j]]*(dis[ssrc[j]]*dis[i])
//            + hW[i]*dis[i]^2          (R3 per-edge norm — proven 3.9e-3)
//
// R5 lesson: atomic k_fill makes bucket order non-deterministic per call ->
// replay revalidation failed. Fix: k_sort (bitonic per bucket) makes the
// whole pipeline bitwise deterministic. Agg speed: 8-edge load batching
// (independent gathers in flight) with an UNCHANGED sequential fma order.

// ---------------- graph preprocessing (CSR by dst, int atomics only) --------

__global__ void k_count(const int* __restrict__ dst, int* __restrict__ cnt, int e) {
    int i = blockIdx.x * 256 + threadIdx.x;
    if (i < e) atomicAdd(&cnt[dst[i]], 1);
}

__global__ void k_dis(const int* __restrict__ cnt, float* __restrict__ dis, int n) {
    int i = blockIdx.x * 256 + threadIdx.x;
    if (i < n) dis[i] = rsqrtf(1.0f + (float)cnt[i]);
}

__global__ void k_blocksum(const int* __restrict__ cnt, int* __restrict__ bsum, int n) {
    __shared__ int sm[256];
    int t = threadIdx.x;
    int base = blockIdx.x * 1024;
    int s = 0;
#pragma unroll
    for (int i = 0; i < 4; i++) {
        int idx = base + i * 256 + t;
        if (idx < n) s += cnt[idx];
    }
    sm[t] = s;
    __syncthreads();
    for (int off = 128; off > 0; off >>= 1) {
        if (t < off) sm[t] += sm[t + off];
        __syncthreads();
    }
    if (t == 0) bsum[blockIdx.x] = sm[0];
}

__global__ void k_scansums(const int* __restrict__ bsum, int* __restrict__ boff, int nb) {
    __shared__ int sm[256];
    int t = threadIdx.x;
    int v = (t < nb) ? bsum[t] : 0;
    sm[t] = v;
    __syncthreads();
    for (int off = 1; off < 256; off <<= 1) {
        int add = (t >= off) ? sm[t - off] : 0;
        __syncthreads();
        sm[t] += add;
        __syncthreads();
    }
    if (t < nb) boff[t] = sm[t] - v;  // exclusive
}

__global__ void k_scatterscan(const int* __restrict__ cnt, const int* __restrict__ boff,
                              int* __restrict__ offs, int n) {
    __shared__ int sm[256];
    int t = threadIdx.x;
    int base = blockIdx.x * 1024 + t * 4;
    int v[4];
    int s = 0;
#pragma unroll
    for (int i = 0; i < 4; i++) {
        int idx = base + i;
        v[i] = (idx < n) ? cnt[idx] : 0;
        s += v[i];
    }
    sm[t] = s;
    __syncthreads();
    for (int off = 1; off < 256; off <<= 1) {
        int add = (t >= off) ? sm[t - off] : 0;
        __syncthreads();
        sm[t] += add;
        __syncthreads();
    }
    int run = boff[blockIdx.x] + sm[t] - s;
#pragma unroll
    for (int i = 0; i < 4; i++) {
        int idx = base + i;
        if (idx < n) {
            offs[idx] = run;
            run += v[i];
            if (idx == n - 1) offs[n] = run;
        }
    }
}

__global__ void k_fill(const int* __restrict__ src, const int* __restrict__ dst,
                       const int* __restrict__ offs, int* __restrict__ cur,
                       int* __restrict__ ssrc, int e) {
    int i = blockIdx.x * 256 + threadIdx.x;
    if (i < e) {
        int d = dst[i];
        int p = offs[d] + atomicAdd(&cur[d], 1);
        ssrc[p] = src[i];
    }
}

// Sort each CSR bucket ascending -> bitwise-deterministic aggregation.
// One wave per node; 64-lane bitonic via shfl_xor; serial fallback deg>64.
__global__ __launch_bounds__(256) void k_sort(const int* __restrict__ offs,
                                              int* __restrict__ ssrc, int n) {
    const int wv = threadIdx.x >> 6;
    const int lane = threadIdx.x & 63;
    const int node = blockIdx.x * 4 + wv;
    if (node >= n) return;
    const int jb = offs[node];
    const int je = offs[node + 1];
    const int len = je - jb;
    if (len <= 1) return;
    if (len <= 64) {
        int v = (lane < len) ? ssrc[jb + lane] : 0x7fffffff;
#pragma unroll
        for (int k = 2; k <= 64; k <<= 1) {
            for (int j = k >> 1; j > 0; j >>= 1) {
                int p = __shfl_xor(v, j);
                bool lower = (lane & j) == 0;
                bool asc = (lane & k) == 0;
                v = (lower == asc) ? min(v, p) : max(v, p);
            }
        }
        if (lane < len) ssrc[jb + lane] = v;
    } else if (lane == 0) {
        for (int a = jb + 1; a < je; a++) {
            int key = ssrc[a];
            int b = a - 1;
            while (b >= jb && ssrc[b] > key) { ssrc[b + 1] = ssrc[b]; b--; }
            ssrc[b + 1] = key;
        }
    }
}

// ---------------- dense matmul: out[n,FOUT] = [in1|in2] @ W -----------------
// Block = 64 nodes x FOUT. 256 threads = 4 f-slices x 64 lanes (lane = node).
// A-tile staged in LDS (coalesced float4); W addresses wave-uniform -> s_load.

template <int FIN1, int FIN2, int FOUT, bool BIAS, bool RELU>
__global__ __launch_bounds__(256) void k_mm(const float* __restrict__ in1,
                                            const float* __restrict__ in2,
                                            const float* __restrict__ W,
                                            const float* __restrict__ bias,
                                            float* __restrict__ out, int n) {
    constexpr int FINT = FIN1 + FIN2;
    constexpr int ROWF = FINT + 4;   // +4 floats pad
    constexpr int JPT = FOUT / 4;    // outputs per thread (32 or 16)
    constexpr int NC4 = JPT / 4;     // float4 accumulators (8 or 4)

    __shared__ float lds[64 * ROWF];

    const int t = threadIdx.x;
    const int base = blockIdx.x * 64;

    {
        constexpr int R4 = FIN1 / 4;
        const float4* g = (const float4*)in1;
        for (int i = t; i < 64 * R4; i += 256) {
            int r = i / R4, c = i % R4;
            float4 v = (base + r < n) ? g[(size_t)(base + r) * R4 + c]
                                      : make_float4(0.f, 0.f, 0.f, 0.f);
            *(float4*)&lds[r * ROWF + c * 4] = v;
        }
    }
    if constexpr (FIN2 > 0) {
        constexpr int R4 = FIN2 / 4;
        const float4* g = (const float4*)in2;
        for (int i = t; i < 64 * R4; i += 256) {
            int r = i / R4, c = i % R4;
            float4 v = (base + r < n) ? g[(size_t)(base + r) * R4 + c]
                                      : make_float4(0.f, 0.f, 0.f, 0.f);
            *(float4*)&lds[r * ROWF + FIN1 + c * 4] = v;
        }
    }
    __syncthreads();

    const int lane = t & 63;
    const int f0 = __builtin_amdgcn_readfirstlane((t >> 6) * JPT);

    float4 c0, c1, c2, c3, c4, c5, c6, c7;
    if (BIAS) {
        const float4* b4 = (const float4*)(bias + f0);
        c0 = b4[0]; c1 = b4[1]; c2 = b4[2]; c3 = b4[3];
        if (NC4 == 8) { c4 = b4[4]; c5 = b4[5]; c6 = b4[6]; c7 = b4[7]; }
        else { c4 = c5 = c6 = c7 = make_float4(0.f, 0.f, 0.f, 0.f); }
    } else {
        c0 = c1 = c2 = c3 = c4 = c5 = c6 = c7 = make_float4(0.f, 0.f, 0.f, 0.f);
    }

#define FMA_BLK(av, wp)                                                                              \
    do {                                                                                             \
        const float4* _w4 = (const float4*)(wp);                                                     \
        { float4 _t = _w4[0]; c0.x = fmaf(av, _t.x, c0.x); c0.y = fmaf(av, _t.y, c0.y);              \
          c0.z = fmaf(av, _t.z, c0.z); c0.w = fmaf(av, _t.w, c0.w); }                                \
        { float4 _t = _w4[1]; c1.x = fmaf(av, _t.x, c1.x); c1.y = fmaf(av, _t.y, c1.y);              \
          c1.z = fmaf(av, _t.z, c1.z); c1.w = fmaf(av, _t.w, c1.w); }                                \
        { float4 _t = _w4[2]; c2.x = fmaf(av, _t.x, c2.x); c2.y = fmaf(av, _t.y, c2.y);              \
          c2.z = fmaf(av, _t.z, c2.z); c2.w = fmaf(av, _t.w, c2.w); }                                \
        { float4 _t = _w4[3]; c3.x = fmaf(av, _t.x, c3.x); c3.y = fmaf(av, _t.y, c3.y);              \
          c3.z = fmaf(av, _t.z, c3.z); c3.w = fmaf(av, _t.w, c3.w); }                                \
        if constexpr (NC4 == 8) {                                                                    \
            { float4 _t = _w4[4]; c4.x = fmaf(av, _t.x, c4.x); c4.y = fmaf(av, _t.y, c4.y);          \
              c4.z = fmaf(av, _t.z, c4.z); c4.w = fmaf(av, _t.w, c4.w); }                            \
            { float4 _t = _w4[5]; c5.x = fmaf(av, _t.x, c5.x); c5.y = fmaf(av, _t.y, c5.y);          \
              c5.z = fmaf(av, _t.z, c5.z); c5.w = fmaf(av, _t.w, c5.w); }                            \
            { float4 _t = _w4[6]; c6.x = fmaf(av, _t.x, c6.x); c6.y = fmaf(av, _t.y, c6.y);          \
              c6.z = fmaf(av, _t.z, c6.z); c6.w = fmaf(av, _t.w, c6.w); }                            \
            { float4 _t = _w4[7]; c7.x = fmaf(av, _t.x, c7.x); c7.y = fmaf(av, _t.y, c7.y);          \
              c7.z = fmaf(av, _t.z, c7.z); c7.w = fmaf(av, _t.w, c7.w); }                            \
        }                                                                                            \
    } while (0)

    const float* arow = &lds[lane * ROWF];
    for (int k = 0; k < FINT; k += 4) {
        float4 a = *(const float4*)(arow + k);
        const float* wr = W + (size_t)k * FOUT + f0;
        FMA_BLK(a.x, wr);
        FMA_BLK(a.y, wr + FOUT);
        FMA_BLK(a.z, wr + 2 * FOUT);
        FMA_BLK(a.w, wr + 3 * FOUT);
    }
#undef FMA_BLK

    const int node = base + lane;
    if (node < n) {
        if (RELU) {
#define RL(c) do { c.x = fmaxf(c.x, 0.f); c.y = fmaxf(c.y, 0.f); \
                   c.z = fmaxf(c.z, 0.f); c.w = fmaxf(c.w, 0.f); } while (0)
            RL(c0); RL(c1); RL(c2); RL(c3);
            if (NC4 == 8) { RL(c4); RL(c5); RL(c6); RL(c7); }
#undef RL
        }
        float4* orow = (float4*)(out + (size_t)node * FOUT + f0);
        orow[0] = c0; orow[1] = c1; orow[2] = c2; orow[3] = c3;
        if (NC4 == 8) { orow[4] = c4; orow[5] = c5; orow[6] = c6; orow[7] = c7; }
    }
}

// ---------------- GCN aggregation (R3 numerics + batched loads) -------------
// out[i] = sum_j hW[ssrc[j]] * (dis[ssrc[j]]*dis[i])   (sequential CSR order)
//        + hW[i]*dis[i]^2 + bias   (optional relu)
// Wave per node, lane owns FPL consecutive features. Loads batched 8 edges
// deep (independent gathers in flight); fma chain order identical to R3.

template <int F, bool RELU>
__global__ __launch_bounds__(256) void k_agg(const float* __restrict__ hW,
                                             const float* __restrict__ bias,
                                             const float* __restrict__ dis,
                                             const int* __restrict__ offs,
                                             const int* __restrict__ ssrc,
                                             float* __restrict__ out, int n) {
    const int wv = threadIdx.x >> 6;
    const int lane = threadIdx.x & 63;
    const int node = blockIdx.x * 4 + wv;
    if (node >= n) return;

    constexpr int FPL = F / 64;  // floats per lane (1 or 2)
    const int jb = offs[node];
    const int je = offs[node + 1];
    const float di = dis[node];
    const float* lbase = hW + lane * FPL;

    float accx = 0.f, accy = 0.f;
    int j = jb;
    for (; j + 8 <= je; j += 8) {
        int s[8];
#pragma unroll
        for (int k = 0; k < 8; k++) s[k] = ssrc[j + k];
        float w[8];
#pragma unroll
        for (int k = 0; k < 8; k++) w[k] = dis[s[k]] * di;
        float hx[8], hy[8];
#pragma unroll
        for (int k = 0; k < 8; k++) {
            if constexpr (FPL == 2) {
                float2 h = *(const float2*)(lbase + (size_t)s[k] * F);
                hx[k] = h.x; hy[k] = h.y;
            } else {
                hx[k] = lbase[(size_t)s[k] * F];
            }
        }
#pragma unroll
        for (int k = 0; k < 8; k++) {
            accx = fmaf(hx[k], w[k], accx);
            if constexpr (FPL == 2) accy = fmaf(hy[k], w[k], accy);
        }
    }
    for (; j < je; j++) {
        int s = ssrc[j];
        float w = dis[s] * di;
        if constexpr (FPL == 2) {
            float2 h = *(const float2*)(lbase + (size_t)s * F);
            accx = fmaf(h.x, w, accx);
            accy = fmaf(h.y, w, accy);
        } else {
            accx = fmaf(lbase[(size_t)s * F], w, accx);
        }
    }

    const float sw = di * di;
    if constexpr (FPL == 2) {
        float2 hs = *(const float2*)(hW + (size_t)node * F + lane * 2);
        float2 bb = *(const float2*)(bias + lane * 2);
        float vx = accx + hs.x * sw + bb.x;
        float vy = accy + hs.y * sw + bb.y;
        if (RELU) { vx = fmaxf(vx, 0.f); vy = fmaxf(vy, 0.f); }
        *(float2*)(out + (size_t)node * F + lane * 2) = make_float2(vx, vy);
    } else {
        float hs = hW[(size_t)node * F + lane];
        float v = accx + hs * sw + bias[lane];
        if (RELU) v = fmaxf(v, 0.f);
        out[(size_t)node * F + lane] = v;
    }
}

// ---------------- launch -----------------------------------------------------

extern "C" void kernel_launch(void* const* d_in, const int* in_sizes, int n_in,
                              void* d_out, int out_size, void* d_ws, size_t ws_size,
                              hipStream_t stream) {
    const float* x   = (const float*)d_in[0];
    const float* st  = (const float*)d_in[1];
    const int*   src = (const int*)d_in[2];
    const int*   dst = (const int*)d_in[3];
    const float* W1  = (const float*)d_in[4];
    const float* b1  = (const float*)d_in[5];
    const float* W2  = (const float*)d_in[6];
    const float* b2  = (const float*)d_in[7];
    const float* Wg0 = (const float*)d_in[8];
    const float* bg0 = (const float*)d_in[9];
    const float* Wg1 = (const float*)d_in[10];
    const float* bg1 = (const float*)d_in[11];
    const float* Wg2 = (const float*)d_in[12];
    const float* bg2 = (const float*)d_in[13];

    const int n = in_sizes[0] / 64;  // IN_DIM = 64
    const int e = in_sizes[2];

    char* wp = (char*)d_ws;
    auto carve = [&](size_t bytes) {
        void* p = (void*)wp;
        wp += (bytes + 255) & ~(size_t)255;
        return p;
    };
    int*   cnt  = (int*)carve((size_t)n * 4);
    int*   cur  = (int*)carve((size_t)n * 4);
    int*   offs = (int*)carve((size_t)(n + 1) * 4);
    float* dis  = (float*)carve((size_t)n * 4);
    int*   ssrc = (int*)carve((size_t)e * 4);
    float* bufA = (float*)carve((size_t)n * 128 * 4);
    float* bufB = (float*)carve((size_t)n * 128 * 4);
    const int nb1024 = (n + 1023) / 1024;
    int* bsum = (int*)carve((size_t)nb1024 * 4);
    int* boff = (int*)carve((size_t)nb1024 * 4);

    hipMemsetAsync(cnt, 0, (size_t)n * 4, stream);
    hipMemsetAsync(cur, 0, (size_t)n * 4, stream);

    const int gE = (e + 255) / 256;
    const int gN = (n + 255) / 256;
    const int gN64 = (n + 63) / 64;
    const int gAgg = (n + 3) / 4;

    // graph prep (ssrc is re-sorted per bucket -> deterministic pipeline)
    k_count<<<gE, 256, 0, stream>>>(dst, cnt, e);
    k_dis<<<gN, 256, 0, stream>>>(cnt, dis, n);
    k_blocksum<<<nb1024, 256, 0, stream>>>(cnt, bsum, n);
    k_scansums<<<1, 256, 0, stream>>>(bsum, boff, nb1024);
    k_scatterscan<<<nb1024, 256, 0, stream>>>(cnt, boff, offs, n);
    k_fill<<<gE, 256, 0, stream>>>(src, dst, offs, cur, ssrc, e);
    k_sort<<<gAgg, 256, 0, stream>>>(offs, ssrc, n);

    // MLP
    k_mm<64, 32, 128, true, true><<<gN64, 256, 0, stream>>>(x, st, W1, b1, bufA, n);
    k_mm<128, 0, 64, true, true><<<gN64, 256, 0, stream>>>(bufA, nullptr, W2, b2, bufB, n);  // h0

    // conv0: mm -> agg@128 (bias+relu fused)
    k_mm<64, 0, 128, false, false><<<gN64, 256, 0, stream>>>(bufB, nullptr, Wg0, nullptr, bufA, n);
    k_agg<128, true><<<gAgg, 256, 0, stream>>>(bufA, bg0, dis, offs, ssrc, bufB, n);  // h1

    // conv1: mm -> agg@128 (bias+relu fused)
    k_mm<128, 0, 128, false, false><<<gN64, 256, 0, stream>>>(bufB, nullptr, Wg1, nullptr, bufA, n);
    k_agg<128, true><<<gAgg, 256, 0, stream>>>(bufA, bg1, dis, offs, ssrc, bufB, n);  // h2

    // conv2: mm -> agg@64 (bias, no relu) -> d_out
    k_mm<128, 0, 64, false, false><<<gN64, 256, 0, stream>>>(bufB, nullptr, Wg2, nullptr, bufA, n);
    k_agg<64, false><<<gAgg, 256, 0, stream>>>(bufA, bg2, dis, offs, ssrc, (float*)d_out, n);
}